// Round 19
// baseline (92.114 us; speedup 1.0000x reference)
//
#include <hip/hip_runtime.h>
#include <hip/hip_bf16.h>

#define B_ROWS 8192
#define C_IN   4096
#define G_GRP  8
#define CG     512
#define J_RANK 512

// ---- GEMM geometry: 128x128 tile, BK=32, 4 waves (2x2), wave tile 64x64 ----
#define BM 128
#define BN 128
#define BK 32
#define NKT (CG / BK)                 // 16 K-tiles

// ---- permute geometry ----
#define RPB    8                      // rows per permute block
#define PERM_BLOCKS (B_ROWS / RPB)    // 1024
#define CONV_BLOCKS 128               // w-conversion folded into same launch

typedef __attribute__((ext_vector_type(8))) short bf16x8;
typedef __attribute__((ext_vector_type(4))) float f32x4;
typedef __attribute__((ext_vector_type(8))) unsigned short u16x8;

struct ushort4v { unsigned short x, y, z, w; };

__device__ __forceinline__ unsigned short f2bf(float f) {
    unsigned int u = __float_as_uint(f);
    unsigned int r = (u + 0x7FFFu + ((u >> 16) & 1u)) >> 16;  // RNE
    return (unsigned short)r;
}

// ------ kernel 1: gather-permute x (REG-STAGED loads) + w-convert --------
// (byte-identical to R17/R18 -- best measured)
__global__ __launch_bounds__(256) void permute_x_kernel(
    const float* __restrict__ x, const int* __restrict__ arr,
    unsigned short* __restrict__ xp,
    const float* __restrict__ w, unsigned short* __restrict__ wb) {
    const int tid = threadIdx.x;

    if (blockIdx.x >= PERM_BLOCKS) {
        // ---- w conversion path ----
        const int cb = blockIdx.x - PERM_BLOCKS;
#pragma unroll
        for (int t = 0; t < 16; ++t) {
            int i = cb * 4096 + t * 256 + tid;   // 128*4096 = 524288 float4s
            float4 v = ((const float4*)w)[i];
            ushort4v o;
            o.x = f2bf(v.x); o.y = f2bf(v.y); o.z = f2bf(v.z); o.w = f2bf(v.w);
            ((ushort4v*)wb)[i] = o;
        }
        return;
    }

    __shared__ float buf[2][C_IN];   // 32 KB -> 5 blocks/CU
    const int row0 = blockIdx.x * RPB;

    // arrangements declared int64 in the reference; harness may hand int32.
    // int64 little-endian => odd int32 words all 0 (values < 4096).
    const bool is64 = (arr[1] == 0 && arr[3] == 0 && arr[5] == 0 && arr[7] == 0);

    int sidx[16];
#pragma unroll
    for (int pass = 0; pass < 2; ++pass)
#pragma unroll
        for (int k = 0; k < 8; ++k) {
            int p = pass * 2048 + tid * 8 + k;
            sidx[pass * 8 + k] = is64 ? arr[2 * p] : arr[p];
        }

    float4 ra[4], rb[4];

#define PLOAD(dst_, r_)                                                      \
    do {                                                                     \
        const float4* s_ = (const float4*)(x + (size_t)(row0 + (r_)) * C_IN);\
        _Pragma("unroll")                                                    \
        for (int i_ = 0; i_ < 4; ++i_) dst_[i_] = s_[i_ * 256 + tid];        \
    } while (0)

#define PROW(regs_, r_)                                                      \
    do {                                                                     \
        float4* d_ = (float4*)&buf[(r_) & 1][0];                             \
        _Pragma("unroll")                                                    \
        for (int i_ = 0; i_ < 4; ++i_) d_[i_ * 256 + tid] = regs_[i_];       \
        asm volatile("s_waitcnt lgkmcnt(0)" ::: "memory");                   \
        __builtin_amdgcn_s_barrier();      /* all waves' row r_ in LDS */    \
        const float* bi_ = &buf[(r_) & 1][0];                                \
        unsigned short* orow_ = xp + (size_t)(row0 + (r_)) * C_IN;           \
        _Pragma("unroll")                                                    \
        for (int pass_ = 0; pass_ < 2; ++pass_) {                            \
            u16x8 o_;                                                        \
            _Pragma("unroll")                                                \
            for (int k_ = 0; k_ < 8; ++k_)                                   \
                o_[k_] = f2bf(bi_[sidx[pass_ * 8 + k_]]);                    \
            *(u16x8*)(orow_ + pass_ * 2048 + tid * 8) = o_;                  \
        }                                                                    \
    } while (0)

    PLOAD(ra, 0);
#pragma unroll
    for (int r = 0; r < RPB; ++r) {
        if (r & 1) {
            if (r + 1 < RPB) PLOAD(ra, r + 1);   // next row in flight
            PROW(rb, r);
        } else {
            if (r + 1 < RPB) PLOAD(rb, r + 1);
            PROW(ra, r);
        }
    }
#undef PLOAD
#undef PROW
}

// -------- kernel 2: grouped GEMM, 128x128/BK32, SINGLE-barrier K-loop ----
// 2048 blocks = 8 g x 64 mt x 4 nt, 4 waves (2x2), 4 blocks/CU (40KB LDS).
// Hazard audit: within a kt both "phases" read the same stable buffers and
// STAGEs hit slots whose last readers drained (MFMA consumed their ds_read
// results, forcing lgkmcnt) before the previous kt-boundary barrier. So ONE
// barrier per kt: {read 8 frags; stage B(kt+1), A(kt+2); 32 MFMA;
// vmcnt(2); s_barrier; sched_barrier}. sched_barrier(0) after s_barrier is
// REQUIRED: the builtin alone is not a compiler fence, and a ds_read
// hoisted above it could see other waves' un-landed DMAs.
// vmcnt ladder (in-order): entering kt: [A(kt+1)]2; +B(kt+1)2 +A(kt+2)2;
// vmcnt(2) retires A/B(kt+1), leaves A(kt+2); vmcnt(0) at kt=NKT-2.
__global__ __launch_bounds__(256, 4) void gemm_kernel(
    const unsigned short* __restrict__ Xp,   // [B][4096] bf16 (permuted)
    const unsigned short* __restrict__ Wb,   // [G][J][CG] bf16
    const float* __restrict__ bias,          // [G][J]
    float* __restrict__ out) {               // [B][4096] fp32
    __shared__ unsigned short ldsA[3][BM * BK];   // 3 x 8 KB
    __shared__ unsigned short ldsB[2][BN * BK];   // 2 x 8 KB

    const int tid = threadIdx.x;
    const int g   = blockIdx.x & 7;    // group -> XCD pin (2048 % 8 == 0)
    const int idx = blockIdx.x >> 3;   // 0..255
    const int mt  = idx >> 2;          // 0..63
    const int nt  = idx & 3;           // 0..3

    const int l   = tid & 63;
    const int wv  = tid >> 6;          // 0..3
    const int wr  = wv >> 1;           // 0..1  (M half: rows wr*64..+63)
    const int wc  = wv & 1;            // 0..1  (N half: cols wc*64..+63)
    const int lr  = l & 15;
    const int lkq = l >> 4;            // 0..3

    const unsigned short* Ab = Xp + (size_t)(mt * BM) * C_IN + g * CG;
    const unsigned short* Bb = Wb + (size_t)g * J_RANK * CG + (size_t)(nt * BN) * CG;

    f32x4 acc[4][4];
#pragma unroll
    for (int m = 0; m < 4; ++m)
#pragma unroll
        for (int n = 0; n < 4; ++n) acc[m][n] = (f32x4){0.f, 0.f, 0.f, 0.f};

    // read offset within a row: chunk lkq, swizzled by row bits 2-3 (=lr>>2)
    const int coff = (lkq ^ ((lr >> 2) & 3)) * 8;

#define STAGE_A(kt_)                                                          \
    do { const int p_ = (kt_) % 3;                                            \
        _Pragma("unroll")                                                     \
        for (int i_ = 0; i_ < 2; ++i_) {                                      \
            int c_ = i_ * 256 + tid;                                          \
            int rl_ = c_ >> 2, gc_ = (c_ & 3) ^ ((rl_ >> 2) & 3);             \
            __builtin_amdgcn_global_load_lds(                                 \
                (const __attribute__((address_space(1))) unsigned int*)       \
                    (Ab + (size_t)rl_ * C_IN + (kt_) * BK + gc_ * 8),         \
                (__attribute__((address_space(3))) unsigned int*)             \
                    (&ldsA[p_][0] + c_ * 8),                                  \
                16, 0, 0);                                                    \
        }                                                                     \
    } while (0)

#define STAGE_B(kt_)                                                          \
    do { const int p_ = (kt_) & 1;                                            \
        _Pragma("unroll")                                                     \
        for (int i_ = 0; i_ < 2; ++i_) {                                      \
            int c_ = i_ * 256 + tid;                                          \
            int rl_ = c_ >> 2, gc_ = (c_ & 3) ^ ((rl_ >> 2) & 3);             \
            __builtin_amdgcn_global_load_lds(                                 \
                (const __attribute__((address_space(1))) unsigned int*)       \
                    (Bb + (size_t)rl_ * CG + (kt_) * BK + gc_ * 8),           \
                (__attribute__((address_space(3))) unsigned int*)             \
                    (&ldsB[p_][0] + c_ * 8),                                  \
                16, 0, 0);                                                    \
        }                                                                     \
    } while (0)

#define LDA(m_) (*(const bf16x8*)&ldsA[bufA][(wr * 64 + (m_) * 16 + lr) * BK + coff])
#define LDB(n_) (*(const bf16x8*)&ldsB[bufB][(wc * 64 + (n_) * 16 + lr) * BK + coff])

    // ---- prologue: A(0), B(0), A(1); wait A0+B0 landed (A1 in flight) ----
    STAGE_A(0); STAGE_B(0);
    STAGE_A(1);
    asm volatile("s_waitcnt vmcnt(2)" ::: "memory");
    __builtin_amdgcn_s_barrier();
    __builtin_amdgcn_sched_barrier(0);

    bf16x8 bfr[4], af[4];

    for (int kt = 0; kt < NKT; ++kt) {
        const int bufA = kt % 3;
        const int bufB = kt & 1;

        // ---- read all 8 fragments of kt ----
#pragma unroll
        for (int n = 0; n < 4; ++n) bfr[n] = LDB(n);
#pragma unroll
        for (int m = 0; m < 4; ++m) af[m] = LDA(m);

        // ---- stage next tiles (slots freed at the previous barrier) ----
        if (kt + 1 < NKT) STAGE_B(kt + 1);
        if (kt + 2 < NKT) STAGE_A(kt + 2);

        // ---- 32 MFMA (compiler inserts lgkmcnt before frag uses) ----
        __builtin_amdgcn_s_setprio(1);
#pragma unroll
        for (int m = 0; m < 4; ++m)
#pragma unroll
            for (int n = 0; n < 4; ++n)
                acc[m][n] = __builtin_amdgcn_mfma_f32_16x16x32_bf16(
                    af[m], bfr[n], acc[m][n], 0, 0, 0);
        __builtin_amdgcn_s_setprio(0);

        // ---- single boundary: kt+1's data landed machine-wide ----
        if (kt + 1 < NKT) {
            if (kt <= NKT - 3) asm volatile("s_waitcnt vmcnt(2)" ::: "memory");
            else               asm volatile("s_waitcnt vmcnt(0)" ::: "memory");
            __builtin_amdgcn_s_barrier();
            __builtin_amdgcn_sched_barrier(0);
        }
    }
#undef STAGE_A
#undef STAGE_B
#undef LDA
#undef LDB

    // epilogue: D frag layout col = lane&15, row = (lane>>4)*4 + r.
    // Nontemporal: out is write-once; keep it from evicting L2 B-panels.
    const int r0 = mt * BM + wr * 64 + (lkq << 2);
    const int cbase = nt * BN + wc * 64 + lr;   // within group's 512 cols
#pragma unroll
    for (int n = 0; n < 4; ++n) {
        int col = cbase + n * 16;
        float bv = bias[g * J_RANK + col];
#pragma unroll
        for (int m = 0; m < 4; ++m) {
            int row = r0 + m * 16;
            float* op = out + (size_t)row * C_IN + g * J_RANK + col;
#pragma unroll
            for (int r = 0; r < 4; ++r)
                __builtin_nontemporal_store(acc[m][n][r] + bv,
                                            op + (size_t)r * C_IN);
        }
    }
}

extern "C" void kernel_launch(void* const* d_in, const int* in_sizes, int n_in,
                              void* d_out, int out_size, void* d_ws, size_t ws_size,
                              hipStream_t stream) {
    const float* x    = (const float*)d_in[0];
    const int*   arr  = (const int*)d_in[1];
    const float* w    = (const float*)d_in[2];
    const float* bias = (const float*)d_in[3];
    float* out = (float*)d_out;

    // workspace: xp bf16 [8192][4096] (64MB) | wb bf16 [8][512][512] (4MB)
    unsigned short* xp = (unsigned short*)d_ws;
    unsigned short* wb = xp + (size_t)B_ROWS * C_IN;

    hipLaunchKernelGGL(permute_x_kernel, dim3(PERM_BLOCKS + CONV_BLOCKS),
                       dim3(256), 0, stream, x, arr, xp, w, wb);
    hipLaunchKernelGGL(gemm_kernel,
                       dim3(G_GRP * (B_ROWS / BM) * (J_RANK / BN)), dim3(256),
                       0, stream, xp, wb, bias, out);
}

// Round 20
// 91.511 us; speedup vs baseline: 1.0066x; 1.0066x over previous
//
#include <hip/hip_runtime.h>
#include <hip/hip_bf16.h>

#define B_ROWS 8192
#define C_IN   4096
#define G_GRP  8
#define CG     512
#define J_RANK 512

// ---- GEMM geometry: 128x128 tile, BK=32, 4 waves (2x2), wave tile 64x64 ----
#define BM 128
#define BN 128
#define BK 32
#define NKT (CG / BK)                 // 16 K-tiles

// ---- permute geometry ----
#define RPB    8                      // rows per permute block
#define PERM_BLOCKS (B_ROWS / RPB)    // 1024
#define CONV_BLOCKS 128               // w-conversion folded into same launch

typedef __attribute__((ext_vector_type(8))) short bf16x8;
typedef __attribute__((ext_vector_type(4))) float f32x4;
typedef __attribute__((ext_vector_type(8))) unsigned short u16x8;

struct ushort4v { unsigned short x, y, z, w; };

__device__ __forceinline__ unsigned short f2bf(float f) {
    unsigned int u = __float_as_uint(f);
    unsigned int r = (u + 0x7FFFu + ((u >> 16) & 1u)) >> 16;  // RNE
    return (unsigned short)r;
}

// ------ kernel 1: gather-permute x (reg-staged, DEPTH-2) + w-convert ----
// R17 structure with a 3-buffer register rotation: row r+2's coalesced
// float4 loads are issued before row r's gather (~1300cy cover > ~900cy
// HBM latency; depth-1 covered only ~500-800cy). LDS hazards unchanged:
// slot r&1 is written after barrier(r-1), by which point every wave's
// row r-2 ds_reads have retired (their gather results fed the stores).
// Register WAR safe: ds_write of rg[(r-1)%3] issues (reads regs) before
// PLOAD(r+2) overwrites the same buffer.
__global__ __launch_bounds__(256) void permute_x_kernel(
    const float* __restrict__ x, const int* __restrict__ arr,
    unsigned short* __restrict__ xp,
    const float* __restrict__ w, unsigned short* __restrict__ wb) {
    const int tid = threadIdx.x;

    if (blockIdx.x >= PERM_BLOCKS) {
        // ---- w conversion path ----
        const int cb = blockIdx.x - PERM_BLOCKS;
#pragma unroll
        for (int t = 0; t < 16; ++t) {
            int i = cb * 4096 + t * 256 + tid;   // 128*4096 = 524288 float4s
            float4 v = ((const float4*)w)[i];
            ushort4v o;
            o.x = f2bf(v.x); o.y = f2bf(v.y); o.z = f2bf(v.z); o.w = f2bf(v.w);
            ((ushort4v*)wb)[i] = o;
        }
        return;
    }

    __shared__ float buf[2][C_IN];   // 32 KB -> 5 blocks/CU
    const int row0 = blockIdx.x * RPB;

    // arrangements declared int64 in the reference; harness may hand int32.
    // int64 little-endian => odd int32 words all 0 (values < 4096).
    const bool is64 = (arr[1] == 0 && arr[3] == 0 && arr[5] == 0 && arr[7] == 0);

    int sidx[16];
#pragma unroll
    for (int pass = 0; pass < 2; ++pass)
#pragma unroll
        for (int k = 0; k < 8; ++k) {
            int p = pass * 2048 + tid * 8 + k;
            sidx[pass * 8 + k] = is64 ? arr[2 * p] : arr[p];
        }

    float4 rg[3][4];

#define PLOAD(dst_, r_)                                                      \
    do {                                                                     \
        const float4* s_ = (const float4*)(x + (size_t)(row0 + (r_)) * C_IN);\
        _Pragma("unroll")                                                    \
        for (int i_ = 0; i_ < 4; ++i_) dst_[i_] = s_[i_ * 256 + tid];        \
    } while (0)

#define PROW(regs_, r_)                                                      \
    do {                                                                     \
        float4* d_ = (float4*)&buf[(r_) & 1][0];                             \
        _Pragma("unroll")                                                    \
        for (int i_ = 0; i_ < 4; ++i_) d_[i_ * 256 + tid] = regs_[i_];       \
        asm volatile("s_waitcnt lgkmcnt(0)" ::: "memory");                   \
        __builtin_amdgcn_s_barrier();      /* all waves' row r_ in LDS */    \
        const float* bi_ = &buf[(r_) & 1][0];                                \
        unsigned short* orow_ = xp + (size_t)(row0 + (r_)) * C_IN;           \
        _Pragma("unroll")                                                    \
        for (int pass_ = 0; pass_ < 2; ++pass_) {                            \
            u16x8 o_;                                                        \
            _Pragma("unroll")                                                \
            for (int k_ = 0; k_ < 8; ++k_)                                   \
                o_[k_] = f2bf(bi_[sidx[pass_ * 8 + k_]]);                    \
            *(u16x8*)(orow_ + pass_ * 2048 + tid * 8) = o_;                  \
        }                                                                    \
    } while (0)

    PLOAD(rg[0], 0);
    PLOAD(rg[1], 1);
#pragma unroll
    for (int r = 0; r < RPB; ++r) {
        if (r + 2 < RPB) PLOAD(rg[(r + 2) % 3], r + 2);   // 2 rows ahead
        PROW(rg[r % 3], r);
    }
#undef PLOAD
#undef PROW
}

// -------- kernel 2: grouped GEMM, 128x128/BK32, 2-phase, 4 blocks/CU ----
// (byte-identical to R18 -- best measured; R19's single-barrier variant
// was neutral, so the simpler 2-phase form is kept)
__global__ __launch_bounds__(256, 4) void gemm_kernel(
    const unsigned short* __restrict__ Xp,   // [B][4096] bf16 (permuted)
    const unsigned short* __restrict__ Wb,   // [G][J][CG] bf16
    const float* __restrict__ bias,          // [G][J]
    float* __restrict__ out) {               // [B][4096] fp32
    __shared__ unsigned short ldsA[3][BM * BK];   // 3 x 8 KB
    __shared__ unsigned short ldsB[2][BN * BK];   // 2 x 8 KB

    const int tid = threadIdx.x;
    const int g   = blockIdx.x & 7;    // group -> XCD pin (2048 % 8 == 0)
    const int idx = blockIdx.x >> 3;   // 0..255
    const int mt  = idx >> 2;          // 0..63
    const int nt  = idx & 3;           // 0..3

    const int l   = tid & 63;
    const int wv  = tid >> 6;          // 0..3
    const int wr  = wv >> 1;           // 0..1  (M half: rows wr*64..+63)
    const int wc  = wv & 1;            // 0..1  (N half: cols wc*64..+63)
    const int lr  = l & 15;
    const int lkq = l >> 4;            // 0..3

    const unsigned short* Ab = Xp + (size_t)(mt * BM) * C_IN + g * CG;
    const unsigned short* Bb = Wb + (size_t)g * J_RANK * CG + (size_t)(nt * BN) * CG;

    f32x4 acc[4][4];
#pragma unroll
    for (int m = 0; m < 4; ++m)
#pragma unroll
        for (int n = 0; n < 4; ++n) acc[m][n] = (f32x4){0.f, 0.f, 0.f, 0.f};

    // read offset within a row: chunk lkq, swizzled by row bits 2-3 (=lr>>2)
    const int coff = (lkq ^ ((lr >> 2) & 3)) * 8;

#define STAGE_A(kt_)                                                          \
    do { const int p_ = (kt_) % 3;                                            \
        _Pragma("unroll")                                                     \
        for (int i_ = 0; i_ < 2; ++i_) {                                      \
            int c_ = i_ * 256 + tid;                                          \
            int rl_ = c_ >> 2, gc_ = (c_ & 3) ^ ((rl_ >> 2) & 3);             \
            __builtin_amdgcn_global_load_lds(                                 \
                (const __attribute__((address_space(1))) unsigned int*)       \
                    (Ab + (size_t)rl_ * C_IN + (kt_) * BK + gc_ * 8),         \
                (__attribute__((address_space(3))) unsigned int*)             \
                    (&ldsA[p_][0] + c_ * 8),                                  \
                16, 0, 0);                                                    \
        }                                                                     \
    } while (0)

#define STAGE_B(kt_)                                                          \
    do { const int p_ = (kt_) & 1;                                            \
        _Pragma("unroll")                                                     \
        for (int i_ = 0; i_ < 2; ++i_) {                                      \
            int c_ = i_ * 256 + tid;                                          \
            int rl_ = c_ >> 2, gc_ = (c_ & 3) ^ ((rl_ >> 2) & 3);             \
            __builtin_amdgcn_global_load_lds(                                 \
                (const __attribute__((address_space(1))) unsigned int*)       \
                    (Bb + (size_t)rl_ * CG + (kt_) * BK + gc_ * 8),           \
                (__attribute__((address_space(3))) unsigned int*)             \
                    (&ldsB[p_][0] + c_ * 8),                                  \
                16, 0, 0);                                                    \
        }                                                                     \
    } while (0)

#define LDA(m_) (*(const bf16x8*)&ldsA[bufA][(wr * 64 + (m_) * 16 + lr) * BK + coff])
#define LDB(n_) (*(const bf16x8*)&ldsB[bufB][(wc * 64 + (n_) * 16 + lr) * BK + coff])

#define PHASE_TAIL()                                                          \
    __builtin_amdgcn_s_barrier();                                             \
    asm volatile("s_waitcnt lgkmcnt(0)" ::: "memory");                        \
    __builtin_amdgcn_sched_barrier(0);                                        \
    __builtin_amdgcn_s_setprio(1)

#define PHASE_END()                                                           \
    __builtin_amdgcn_s_setprio(0);                                            \
    __builtin_amdgcn_s_barrier()

    // ---- prologue: A(0), B(0), A(1); wait A0+B0 landed (A1 in flight) ----
    STAGE_A(0); STAGE_B(0);
    STAGE_A(1);
    asm volatile("s_waitcnt vmcnt(2)" ::: "memory");
    __builtin_amdgcn_s_barrier();

    bf16x8 bfr[4], af[2];

    for (int kt = 0; kt < NKT; ++kt) {
        const int bufA = kt % 3;
        const int bufB = kt & 1;

        // ---- phase 0: read B(all 4) + A(m0,m1); stage B(kt+1), A(kt+2) ----
#pragma unroll
        for (int n = 0; n < 4; ++n) bfr[n] = LDB(n);
        af[0] = LDA(0); af[1] = LDA(1);
        if (kt + 1 < NKT) STAGE_B(kt + 1);
        if (kt + 2 < NKT) STAGE_A(kt + 2);
        PHASE_TAIL();
#pragma unroll
        for (int mm = 0; mm < 2; ++mm)
#pragma unroll
            for (int n = 0; n < 4; ++n)
                acc[mm][n] = __builtin_amdgcn_mfma_f32_16x16x32_bf16(
                    af[mm], bfr[n], acc[mm][n], 0, 0, 0);
        PHASE_END();

        // ---- phase 1: read A(m2,m3); counted vmcnt for (kt+1)'s buffers ----
        af[0] = LDA(2); af[1] = LDA(3);
        if (kt <= NKT - 3)      asm volatile("s_waitcnt vmcnt(2)" ::: "memory");
        else                    asm volatile("s_waitcnt vmcnt(0)" ::: "memory");
        PHASE_TAIL();
#pragma unroll
        for (int mm = 0; mm < 2; ++mm)
#pragma unroll
            for (int n = 0; n < 4; ++n)
                acc[2 + mm][n] = __builtin_amdgcn_mfma_f32_16x16x32_bf16(
                    af[mm], bfr[n], acc[2 + mm][n], 0, 0, 0);
        PHASE_END();
    }
#undef STAGE_A
#undef STAGE_B
#undef LDA
#undef LDB
#undef PHASE_TAIL
#undef PHASE_END

    // epilogue: D frag layout col = lane&15, row = (lane>>4)*4 + r.
    // Nontemporal: out is write-once; keep it from evicting L2 B-panels.
    const int r0 = mt * BM + wr * 64 + (lkq << 2);
    const int cbase = nt * BN + wc * 64 + lr;   // within group's 512 cols
#pragma unroll
    for (int n = 0; n < 4; ++n) {
        int col = cbase + n * 16;
        float bv = bias[g * J_RANK + col];
#pragma unroll
        for (int m = 0; m < 4; ++m) {
            int row = r0 + m * 16;
            float* op = out + (size_t)row * C_IN + g * J_RANK + col;
#pragma unroll
            for (int r = 0; r < 4; ++r)
                __builtin_nontemporal_store(acc[m][n][r] + bv,
                                            op + (size_t)r * C_IN);
        }
    }
}

extern "C" void kernel_launch(void* const* d_in, const int* in_sizes, int n_in,
                              void* d_out, int out_size, void* d_ws, size_t ws_size,
                              hipStream_t stream) {
    const float* x    = (const float*)d_in[0];
    const int*   arr  = (const int*)d_in[1];
    const float* w    = (const float*)d_in[2];
    const float* bias = (const float*)d_in[3];
    float* out = (float*)d_out;

    // workspace: xp bf16 [8192][4096] (64MB) | wb bf16 [8][512][512] (4MB)
    unsigned short* xp = (unsigned short*)d_ws;
    unsigned short* wb = xp + (size_t)B_ROWS * C_IN;

    hipLaunchKernelGGL(permute_x_kernel, dim3(PERM_BLOCKS + CONV_BLOCKS),
                       dim3(256), 0, stream, x, arr, xp, w, wb);
    hipLaunchKernelGGL(gemm_kernel,
                       dim3(G_GRP * (B_ROWS / BM) * (J_RANK / BN)), dim3(256),
                       0, stream, xp, wb, bias, out);
}